// Round 10
// baseline (154.391 us; speedup 1.0000x reference)
//
#include <hip/hip_runtime.h>

typedef unsigned short ushort_t;
typedef __attribute__((ext_vector_type(8))) short short8;
typedef __attribute__((ext_vector_type(4))) float f32x4;
typedef __attribute__((ext_vector_type(4))) unsigned short ushort4v;
typedef __attribute__((ext_vector_type(8))) unsigned short ushort8v;

#define S_LEN 2048
#define D_MODEL 1024
#define NH 16
#define NKV 4
#define HD 64

// fp32 -> bf16 round-to-nearest-even
__device__ __forceinline__ ushort_t f2bf(float f) {
    unsigned u = __float_as_uint(f);
    u += 0x7fffu + ((u >> 16) & 1u);
    return (ushort_t)(u >> 16);
}

// async global->LDS, 16B/lane; LDS base wave-uniform, HW scatters lane*16
__device__ __forceinline__ void cp16(void* lds, const void* g) {
    __builtin_amdgcn_global_load_lds(
        (__attribute__((address_space(1))) void*)g,
        (__attribute__((address_space(3))) void*)lds, 16, 0, 0);
}

// ---------------------------------------------------------------------------
// Preprocess: z=0..3 -> weight transpose+cast W[k][n] fp32 -> WT[n][k] bf16;
// z=4 -> x fp32 -> bf16 (8 chunks of 256K elems). grid (16,16,5).
// ---------------------------------------------------------------------------
__global__ __launch_bounds__(256) void prep_kernel(
    const float* __restrict__ x, ushort_t* __restrict__ xb,
    const float* __restrict__ Wq, const float* __restrict__ Wk,
    const float* __restrict__ Wv, const float* __restrict__ Wo,
    ushort_t* __restrict__ WqT, ushort_t* __restrict__ WkT,
    ushort_t* __restrict__ WvT, ushort_t* __restrict__ WoT)
{
    const int t = threadIdx.x;
    if (blockIdx.z == 4) {
        const int b  = blockIdx.y * 16 + blockIdx.x;
        const int i0 = (b * 256 + t) * 4;
        #pragma unroll
        for (int rep = 0; rep < 8; ++rep) {
            const int i = i0 + rep * 262144;   // 8 x 256K covers 2048*1024
            float4 v = *(const float4*)(x + i);
            ushort4v o = { f2bf(v.x), f2bf(v.y), f2bf(v.z), f2bf(v.w) };
            *(ushort4v*)(xb + i) = o;
        }
        return;
    }
    __shared__ ushort_t T[64 * 72];
    const float* W; ushort_t* WT; int N;
    switch (blockIdx.z) {
        case 0:  W = Wq; WT = WqT; N = 1024; break;
        case 1:  W = Wk; WT = WkT; N = 256;  break;
        case 2:  W = Wv; WT = WvT; N = 256;  break;
        default: W = Wo; WT = WoT; N = 1024; break;
    }
    const int n0 = blockIdx.y * 64;
    if (n0 >= N) return;
    const int k0 = blockIdx.x * 64;
    const int kr = t >> 4, nc = (t & 15) * 4;
    #pragma unroll
    for (int p = 0; p < 4; ++p) {
        const int k = kr + p * 16;
        float4 v = *(const float4*)(W + (size_t)(k0 + k) * N + n0 + nc);
        T[(nc + 0) * 72 + k] = f2bf(v.x);
        T[(nc + 1) * 72 + k] = f2bf(v.y);
        T[(nc + 2) * 72 + k] = f2bf(v.z);
        T[(nc + 3) * 72 + k] = f2bf(v.w);
    }
    __syncthreads();
    const int n = t >> 2, seg = (t & 3) * 16;
    ushort8v a = *(ushort8v*)&T[n * 72 + seg];
    ushort8v b = *(ushort8v*)&T[n * 72 + seg + 8];
    *(ushort8v*)(WT + (size_t)(n0 + n) * 1024 + k0 + seg)     = a;
    *(ushort8v*)(WT + (size_t)(n0 + n) * 1024 + k0 + seg + 8) = b;
}

// ---------------------------------------------------------------------------
// QKV projection (r8 shape: 64x128, BK=64, dbuf XOR-swizzled LDS).
// grid (32, 12): cy 0..7 -> Q, 8..9 -> K, 10..11 -> V. Fused RoPE epilogue;
// Q additionally scaled by 0.125 (softmax scale folded in -> attn skips it).
// ---------------------------------------------------------------------------
__global__ __launch_bounds__(256, 2) void gemm_qkv_mfma(
    const ushort_t* __restrict__ xb, const ushort_t* __restrict__ WqT,
    const ushort_t* __restrict__ WkT, const ushort_t* __restrict__ WvT,
    const float* __restrict__ rc, const float* __restrict__ rs,
    ushort_t* __restrict__ Qb, ushort_t* __restrict__ Kb,
    ushort_t* __restrict__ Vtb)
{
    __shared__ ushort_t As[2][64 * 64];    // 16 KB
    __shared__ ushort_t Bs[2][128 * 64];   // 32 KB

    const int t = threadIdx.x;
    const int lane = t & 63, wave = t >> 6;
    const int wr = wave >> 1, wc = wave & 1;
    const int quad = lane >> 4, l15 = lane & 15;
    const int lq = lane >> 3, lr = lane & 7;
    const int swz_st = (lr ^ lq) * 8;
    const int l7 = l15 & 7;
    const int fsw0 = (quad ^ l7) * 8;
    const int fsw1 = ((quad + 4) ^ l7) * 8;

    const int m0 = blockIdx.x * 64;
    const int cy = blockIdx.y;

    const ushort_t* WT; int nloc;
    if (cy < 8)       { WT = WqT; nloc = cy * 128; }
    else if (cy < 10) { WT = WkT; nloc = (cy - 8) * 128; }
    else              { WT = WvT; nloc = (cy - 10) * 128; }

    f32x4 acc[2][4];
    #pragma unroll
    for (int i = 0; i < 2; ++i)
        #pragma unroll
        for (int j = 0; j < 4; ++j) acc[i][j] = (f32x4)0.f;

    auto stage = [&](int buf, int k0) {
        #pragma unroll
        for (int i = 0; i < 2; ++i) {
            const int r = wave * 16 + i * 8 + lq;
            cp16(&As[buf][(wave * 16 + i * 8) * 64],
                 xb + (size_t)(m0 + r) * 1024 + k0 + swz_st);
        }
        #pragma unroll
        for (int i = 0; i < 4; ++i) {
            const int r = wave * 32 + i * 8 + lq;
            cp16(&Bs[buf][(wave * 32 + i * 8) * 64],
                 WT + (size_t)(nloc + r) * 1024 + k0 + swz_st);
        }
    };

    stage(0, 0);
    __syncthreads();

    for (int kk = 0; kk < 16; ++kk) {
        const int cur = kk & 1;
        if (kk + 1 < 16) stage(cur ^ 1, (kk + 1) * 64);

        const ushort_t* Ac = &As[cur][0];
        const ushort_t* Bc = &Bs[cur][0];
        #pragma unroll
        for (int hh = 0; hh < 2; ++hh) {
            const int fsw = hh ? fsw1 : fsw0;
            short8 av[2], bv[4];
            #pragma unroll
            for (int i = 0; i < 2; ++i)
                av[i] = *(const short8*)&Ac[(wr * 32 + i * 16 + l15) * 64 + fsw];
            #pragma unroll
            for (int j = 0; j < 4; ++j)
                bv[j] = *(const short8*)&Bc[(wc * 64 + j * 16 + l15) * 64 + fsw];
            #pragma unroll
            for (int i = 0; i < 2; ++i)
                #pragma unroll
                for (int j = 0; j < 4; ++j)
                    acc[i][j] = __builtin_amdgcn_mfma_f32_16x16x32_bf16(
                        av[i], bv[j], acc[i][j], 0, 0, 0);
        }
        __syncthreads();
    }

    // epilogue: C/D layout col = l15 (+16j), row = quad*4+reg (+16i)  [m89]
    if (cy < 10) {
        ushort_t* dst = (cy < 8) ? Qb : Kb;
        const float qs = (cy < 8) ? 0.125f : 1.0f;   // fold softmax scale into Q
        const int h = ((cy < 8) ? cy : (cy - 8)) * 2 + wc;
        #pragma unroll
        for (int i = 0; i < 2; ++i) {
            #pragma unroll
            for (int j = 0; j < 2; ++j) {
                const int d = j * 16 + l15;
                #pragma unroll
                for (int reg = 0; reg < 4; ++reg) {
                    const int s = m0 + wr * 32 + i * 16 + quad * 4 + reg;
                    const float c  = rc[s * 32 + d];
                    const float sn = rs[s * 32 + d];
                    const float v1 = acc[i][j][reg];
                    const float v2 = acc[i][j + 2][reg];
                    dst[((size_t)h * S_LEN + s) * HD + d]      = f2bf((v1 * c - v2 * sn) * qs);
                    dst[((size_t)h * S_LEN + s) * HD + d + 32] = f2bf((v2 * c + v1 * sn) * qs);
                }
            }
        }
    } else {
        const int vh = (cy - 10) * 2 + wc;
        #pragma unroll
        for (int i = 0; i < 2; ++i) {
            const int s0 = m0 + wr * 32 + i * 16 + quad * 4;
            #pragma unroll
            for (int j = 0; j < 4; ++j) {
                const int d = j * 16 + l15;
                ushort4v o = { f2bf(acc[i][j][0]), f2bf(acc[i][j][1]),
                               f2bf(acc[i][j][2]), f2bf(acc[i][j][3]) };
                *(ushort4v*)&Vtb[((size_t)vh * HD + d) * S_LEN + s0] = o;
            }
        }
    }
}

// ---------------------------------------------------------------------------
// MFMA flash attention, M=32 per wave. Block = 128 threads (2 waves x 32
// q-rows = 64-row q-tile). grid (NH, 32) = 512 blocks -> 2 blocks/CU, snake
// pairing preserved. Same 16 K/V ds_read_b128 per wave now feed 32 MFMA
// (ratio 2x vs r8's M=16) -> per-CU LDS frag traffic halves. P tile XOR-seg
// swizzled (stride 64): writes ~2-way (free), reads b128-aligned via fsw.
// P packed by truncation (1 VALU); row-sums kept in fp32. Scale pre-folded
// into Q. Max-free softmax, one final shuffle-reduce.
// ---------------------------------------------------------------------------
__global__ __launch_bounds__(128, 2) void attn_mfma(
    const ushort_t* __restrict__ Qb, const ushort_t* __restrict__ Kb,
    const ushort_t* __restrict__ Vtb, ushort_t* __restrict__ attnb)
{
    __shared__ ushort_t Ks[2][2][64 * 64];   // 32 KB [buf][sub][kv][d] swizzled
    __shared__ ushort_t Vs[2][2][64 * 64];   // 32 KB [buf][sub][d][kv] swizzled
    __shared__ ushort_t Ps[2][32 * 64];      // 8 KB wave-private P, swizzled

    const int t = threadIdx.x;
    const int lane = t & 63, wave = t >> 6;          // wave 0..1
    const int quad = lane >> 4, l15 = lane & 15;
    const int lq = lane >> 3, lr = lane & 7;
    const int swz_st = (lr ^ lq) * 8;
    const int l7 = l15 & 7;
    const int fsw0 = (quad ^ l7) * 8;
    const int fsw1 = ((quad + 4) ^ l7) * 8;

    const int h  = blockIdx.x;
    const int y  = blockIdx.y;
    const int qt = (y < 16) ? y : 47 - y;            // CU pairs: const 33 subtiles
    const int q0 = qt * 64;
    const int kvh = h >> 2;
    const int wrow0 = q0 + wave * 32;                // wave's first q-row

    const ushort_t* Qg = Qb + ((size_t)h * S_LEN + wrow0) * HD;
    const ushort_t* Kg = Kb + (size_t)kvh * S_LEN * HD;
    const ushort_t* Vg = Vtb + (size_t)kvh * HD * S_LEN;

    // Q A-frags (pre-scaled by 0.125): A[m=l15][k=quad*8+j], 2 row tiles
    short8 aq[2][2];
    #pragma unroll
    for (int i = 0; i < 2; ++i) {
        aq[i][0] = *(const short8*)(Qg + (size_t)(i * 16 + l15) * HD + quad * 8);
        aq[i][1] = *(const short8*)(Qg + (size_t)(i * 16 + l15) * HD + 32 + quad * 8);
    }

    float ps[2][4];
    f32x4 Oacc[2][4];
    #pragma unroll
    for (int i = 0; i < 2; ++i)
        #pragma unroll
        for (int jb = 0; jb < 4; ++jb) { Oacc[i][jb] = (f32x4)0.f; ps[i][jb] = 0.f; }
    // note: ps[i][reg] indexed by reg below (4 regs), reuse array shape

    const int nround = (qt + 2) >> 1;   // rounds of 128 KV cols

    auto stage = [&](int buf, int kvbase) {
        #pragma unroll
        for (int u = 0; u < 2; ++u)
            #pragma unroll
            for (int i = 0; i < 4; ++i) {
                const int r = wave * 32 + i * 8 + lq;
                cp16(&Ks[buf][u][(wave * 32 + i * 8) * 64],
                     Kg + (size_t)(kvbase + u * 64 + r) * 64 + swz_st);
                cp16(&Vs[buf][u][(wave * 32 + i * 8) * 64],
                     Vg + (size_t)r * 2048 + kvbase + u * 64 + swz_st);
            }
    };

    stage(0, 0);
    __syncthreads();

    ushort_t* Pw = &Ps[wave][0];

    for (int round = 0; round < nround; ++round) {
        const int cur = round & 1;
        if (round + 1 < nround) stage(cur ^ 1, (round + 1) * 128);

        #pragma unroll
        for (int u = 0; u < 2; ++u) {
            const int kv0 = round * 128 + u * 64;
            if (kv0 > q0 + 63) break;        // fully masked sub-tile
            const ushort_t* Kc = &Ks[cur][u][0];
            const ushort_t* Vc = &Vs[cur][u][0];

            // S = Q K^T  (M=32: K frags shared across both row tiles)
            f32x4 sv[2][4];
            #pragma unroll
            for (int jb = 0; jb < 4; ++jb) {
                short8 b0 = *(const short8*)&Kc[(jb * 16 + l15) * 64 + fsw0];
                short8 b1 = *(const short8*)&Kc[(jb * 16 + l15) * 64 + fsw1];
                #pragma unroll
                for (int i = 0; i < 2; ++i) {
                    f32x4 z = (f32x4)0.f;
                    z = __builtin_amdgcn_mfma_f32_16x16x32_bf16(aq[i][0], b0, z, 0, 0, 0);
                    z = __builtin_amdgcn_mfma_f32_16x16x32_bf16(aq[i][1], b1, z, 0, 0, 0);
                    sv[i][jb] = z;
                }
            }

            // max-free softmax: P = exp(s) (scale pre-folded into Q);
            // mask only on the diagonal sub-tile. Row sums in fp32.
            const bool diag = (kv0 == q0);
            #pragma unroll
            for (int i = 0; i < 2; ++i)
                #pragma unroll
                for (int jb = 0; jb < 4; ++jb) {
                    const int col = kv0 + jb * 16 + l15;
                    #pragma unroll
                    for (int reg = 0; reg < 4; ++reg) {
                        float e = __expf(sv[i][jb][reg]);
                        if (diag && col > wrow0 + i * 16 + quad * 4 + reg) e = 0.f;
                        sv[i][jb][reg] = e;
                        ps[i][reg] += e;
                    }
                }

            // P: C-layout -> swizzled wave-private LDS (truncation pack)
            #pragma unroll
            for (int i = 0; i < 2; ++i)
                #pragma unroll
                for (int jb = 0; jb < 4; ++jb)
                    #pragma unroll
                    for (int reg = 0; reg < 4; ++reg) {
                        const int row = i * 16 + quad * 4 + reg;
                        const int seg = (jb * 2 + (l15 >> 3)) ^ (row & 7);
                        Pw[row * 64 + seg * 8 + (l15 & 7)] =
                            (ushort_t)(__float_as_uint(sv[i][jb][reg]) >> 16);
                    }

            // A-frags of P (same fsw swizzle as K/V)
            short8 pf[2][2];
            #pragma unroll
            for (int i = 0; i < 2; ++i) {
                pf[i][0] = *(const short8*)&Pw[(i * 16 + l15) * 64 + fsw0];
                pf[i][1] = *(const short8*)&Pw[(i * 16 + l15) * 64 + fsw1];
            }

            // O += P V  (V frags shared across both row tiles)
            #pragma unroll
            for (int jb = 0; jb < 4; ++jb) {
                short8 v0 = *(const short8*)&Vc[(jb * 16 + l15) * 64 + fsw0];
                short8 v1 = *(const short8*)&Vc[(jb * 16 + l15) * 64 + fsw1];
                #pragma unroll
                for (int i = 0; i < 2; ++i) {
                    Oacc[i][jb] = __builtin_amdgcn_mfma_f32_16x16x32_bf16(
                        pf[i][0], v0, Oacc[i][jb], 0, 0, 0);
                    Oacc[i][jb] = __builtin_amdgcn_mfma_f32_16x16x32_bf16(
                        pf[i][1], v1, Oacc[i][jb], 0, 0, 0);
                }
            }
        }

        __syncthreads();   // drain stage(round+1), guard buffer reuse
    }

    // final row-sum reduction + normalize + store
    #pragma unroll
    for (int i = 0; i < 2; ++i)
        #pragma unroll
        for (int reg = 0; reg < 4; ++reg) {
            float l = ps[i][reg];
            l += __shfl_xor(l, 1);
            l += __shfl_xor(l, 2);
            l += __shfl_xor(l, 4);
            l += __shfl_xor(l, 8);
            const float inv = 1.f / l;
            const int s = wrow0 + i * 16 + quad * 4 + reg;
            #pragma unroll
            for (int jb = 0; jb < 4; ++jb)
                attnb[(size_t)s * D_MODEL + h * HD + jb * 16 + l15] =
                    f2bf(Oacc[i][jb][reg] * inv);
        }
}

// ---------------------------------------------------------------------------
// Output projection. 64x64 tile, BK=64, swizzled dbuf LDS.
// grid (32, 16) = 512 blocks -> 2 blocks/CU. fp32 out.
// ---------------------------------------------------------------------------
__global__ __launch_bounds__(256, 2) void gemm_out_mfma(
    const ushort_t* __restrict__ Ab, const ushort_t* __restrict__ WoT,
    float* __restrict__ out)
{
    __shared__ ushort_t As[2][64 * 64];
    __shared__ ushort_t Bs[2][64 * 64];

    const int t = threadIdx.x;
    const int lane = t & 63, wave = t >> 6;
    const int wr = wave >> 1, wc = wave & 1;
    const int quad = lane >> 4, l15 = lane & 15;
    const int lq = lane >> 3, lr = lane & 7;
    const int swz_st = (lr ^ lq) * 8;
    const int l7 = l15 & 7;
    const int fsw0 = (quad ^ l7) * 8;
    const int fsw1 = ((quad + 4) ^ l7) * 8;

    const int m0 = blockIdx.x * 64;
    const int n0 = blockIdx.y * 64;

    f32x4 acc[2][2];
    #pragma unroll
    for (int i = 0; i < 2; ++i)
        #pragma unroll
        for (int j = 0; j < 2; ++j) acc[i][j] = (f32x4)0.f;

    auto stage = [&](int buf, int k0) {
        #pragma unroll
        for (int i = 0; i < 2; ++i) {
            const int r = wave * 16 + i * 8 + lq;
            cp16(&As[buf][(wave * 16 + i * 8) * 64],
                 Ab + (size_t)(m0 + r) * 1024 + k0 + swz_st);
            cp16(&Bs[buf][(wave * 16 + i * 8) * 64],
                 WoT + (size_t)(n0 + r) * 1024 + k0 + swz_st);
        }
    };

    stage(0, 0);
    __syncthreads();

    for (int kk = 0; kk < 16; ++kk) {
        const int cur = kk & 1;
        if (kk + 1 < 16) stage(cur ^ 1, (kk + 1) * 64);

        const ushort_t* Ac = &As[cur][0];
        const ushort_t* Bc = &Bs[cur][0];
        #pragma unroll
        for (int hh = 0; hh < 2; ++hh) {
            const int fsw = hh ? fsw1 : fsw0;
            short8 av[2], bv[2];
            #pragma unroll
            for (int i = 0; i < 2; ++i)
                av[i] = *(const short8*)&Ac[(wr * 32 + i * 16 + l15) * 64 + fsw];
            #pragma unroll
            for (int j = 0; j < 2; ++j)
                bv[j] = *(const short8*)&Bc[(wc * 32 + j * 16 + l15) * 64 + fsw];
            #pragma unroll
            for (int i = 0; i < 2; ++i)
                #pragma unroll
                for (int j = 0; j < 2; ++j)
                    acc[i][j] = __builtin_amdgcn_mfma_f32_16x16x32_bf16(
                        av[i], bv[j], acc[i][j], 0, 0, 0);
        }
        __syncthreads();
    }

    #pragma unroll
    for (int i = 0; i < 2; ++i)
        #pragma unroll
        for (int reg = 0; reg < 4; ++reg) {
            const int s = m0 + wr * 32 + i * 16 + quad * 4 + reg;
            #pragma unroll
            for (int j = 0; j < 2; ++j)
                out[(size_t)s * D_MODEL + n0 + wc * 32 + j * 16 + l15] = acc[i][j][reg];
        }
}

// ---------------------------------------------------------------------------
extern "C" void kernel_launch(void* const* d_in, const int* in_sizes, int n_in,
                              void* d_out, int out_size, void* d_ws, size_t ws_size,
                              hipStream_t stream)
{
    const float* x  = (const float*)d_in[0];
    const float* rc = (const float*)d_in[1];
    const float* rs = (const float*)d_in[2];
    const float* Wq = (const float*)d_in[3];
    const float* Wk = (const float*)d_in[4];
    const float* Wv = (const float*)d_in[5];
    const float* Wo = (const float*)d_in[6];
    float* out = (float*)d_out;

    ushort_t* xb   = (ushort_t*)d_ws;                          // 2048*1024
    ushort_t* WqT  = xb   + (size_t)2048 * 1024;               // 1024*1024
    ushort_t* WkT  = WqT  + (size_t)1024 * 1024;               //  256*1024
    ushort_t* WvT  = WkT  + (size_t)256 * 1024;                //  256*1024
    ushort_t* WoT  = WvT  + (size_t)256 * 1024;                // 1024*1024
    ushort_t* Qb   = WoT  + (size_t)1024 * 1024;               // 16*2048*64
    ushort_t* Kb   = Qb   + (size_t)NH * S_LEN * HD;           //  4*2048*64
    ushort_t* Vtb  = Kb   + (size_t)NKV * S_LEN * HD;          //  4*64*2048
    ushort_t* attnb= Vtb  + (size_t)NKV * HD * S_LEN;          // 2048*1024

    prep_kernel<<<dim3(16, 16, 5), 256, 0, stream>>>(x, xb, Wq, Wk, Wv, Wo,
                                                     WqT, WkT, WvT, WoT);
    gemm_qkv_mfma<<<dim3(32, 12), 256, 0, stream>>>(xb, WqT, WkT, WvT,
                                                    rc, rs, Qb, Kb, Vtb);
    attn_mfma<<<dim3(NH, 32), 128, 0, stream>>>(Qb, Kb, Vtb, attnb);
    gemm_out_mfma<<<dim3(32, 16), 256, 0, stream>>>(attnb, WoT, out);
}

// Round 11
// 146.546 us; speedup vs baseline: 1.0535x; 1.0535x over previous
//
#include <hip/hip_runtime.h>

typedef unsigned short ushort_t;
typedef __attribute__((ext_vector_type(8))) short short8;
typedef __attribute__((ext_vector_type(4))) float f32x4;
typedef __attribute__((ext_vector_type(4))) unsigned short ushort4v;
typedef __attribute__((ext_vector_type(8))) unsigned short ushort8v;

#define S_LEN 2048
#define D_MODEL 1024
#define NH 16
#define NKV 4
#define HD 64

// fp32 -> bf16 round-to-nearest-even
__device__ __forceinline__ ushort_t f2bf(float f) {
    unsigned u = __float_as_uint(f);
    u += 0x7fffu + ((u >> 16) & 1u);
    return (ushort_t)(u >> 16);
}

// async global->LDS, 16B/lane; LDS base wave-uniform, HW scatters lane*16
__device__ __forceinline__ void cp16(void* lds, const void* g) {
    __builtin_amdgcn_global_load_lds(
        (__attribute__((address_space(1))) void*)g,
        (__attribute__((address_space(3))) void*)lds, 16, 0, 0);
}

// ---------------------------------------------------------------------------
// Preprocess: z=0..3 -> weight transpose+cast W[k][n] fp32 -> WT[n][k] bf16;
// z=4 -> x fp32 -> bf16 (8 chunks of 256K elems). grid (16,16,5).
// ---------------------------------------------------------------------------
__global__ __launch_bounds__(256) void prep_kernel(
    const float* __restrict__ x, ushort_t* __restrict__ xb,
    const float* __restrict__ Wq, const float* __restrict__ Wk,
    const float* __restrict__ Wv, const float* __restrict__ Wo,
    ushort_t* __restrict__ WqT, ushort_t* __restrict__ WkT,
    ushort_t* __restrict__ WvT, ushort_t* __restrict__ WoT)
{
    const int t = threadIdx.x;
    if (blockIdx.z == 4) {
        const int b  = blockIdx.y * 16 + blockIdx.x;
        const int i0 = (b * 256 + t) * 4;
        #pragma unroll
        for (int rep = 0; rep < 8; ++rep) {
            const int i = i0 + rep * 262144;
            float4 v = *(const float4*)(x + i);
            ushort4v o = { f2bf(v.x), f2bf(v.y), f2bf(v.z), f2bf(v.w) };
            *(ushort4v*)(xb + i) = o;
        }
        return;
    }
    __shared__ ushort_t T[64 * 72];
    const float* W; ushort_t* WT; int N;
    switch (blockIdx.z) {
        case 0:  W = Wq; WT = WqT; N = 1024; break;
        case 1:  W = Wk; WT = WkT; N = 256;  break;
        case 2:  W = Wv; WT = WvT; N = 256;  break;
        default: W = Wo; WT = WoT; N = 1024; break;
    }
    const int n0 = blockIdx.y * 64;
    if (n0 >= N) return;
    const int k0 = blockIdx.x * 64;
    const int kr = t >> 4, nc = (t & 15) * 4;
    #pragma unroll
    for (int p = 0; p < 4; ++p) {
        const int k = kr + p * 16;
        float4 v = *(const float4*)(W + (size_t)(k0 + k) * N + n0 + nc);
        T[(nc + 0) * 72 + k] = f2bf(v.x);
        T[(nc + 1) * 72 + k] = f2bf(v.y);
        T[(nc + 2) * 72 + k] = f2bf(v.z);
        T[(nc + 3) * 72 + k] = f2bf(v.w);
    }
    __syncthreads();
    const int n = t >> 2, seg = (t & 3) * 16;
    ushort8v a = *(ushort8v*)&T[n * 72 + seg];
    ushort8v b = *(ushort8v*)&T[n * 72 + seg + 8];
    *(ushort8v*)(WT + (size_t)(n0 + n) * 1024 + k0 + seg)     = a;
    *(ushort8v*)(WT + (size_t)(n0 + n) * 1024 + k0 + seg + 8) = b;
}

// ---------------------------------------------------------------------------
// QKV projection (64x128, BK=64, dbuf XOR-swizzled LDS). grid (32, 12).
// Fused RoPE; Q pre-scaled by 0.125 (softmax scale folded in).
// ---------------------------------------------------------------------------
__global__ __launch_bounds__(256, 2) void gemm_qkv_mfma(
    const ushort_t* __restrict__ xb, const ushort_t* __restrict__ WqT,
    const ushort_t* __restrict__ WkT, const ushort_t* __restrict__ WvT,
    const float* __restrict__ rc, const float* __restrict__ rs,
    ushort_t* __restrict__ Qb, ushort_t* __restrict__ Kb,
    ushort_t* __restrict__ Vtb)
{
    __shared__ ushort_t As[2][64 * 64];
    __shared__ ushort_t Bs[2][128 * 64];

    const int t = threadIdx.x;
    const int lane = t & 63, wave = t >> 6;
    const int wr = wave >> 1, wc = wave & 1;
    const int quad = lane >> 4, l15 = lane & 15;
    const int lq = lane >> 3, lr = lane & 7;
    const int swz_st = (lr ^ lq) * 8;
    const int l7 = l15 & 7;
    const int fsw0 = (quad ^ l7) * 8;
    const int fsw1 = ((quad + 4) ^ l7) * 8;

    const int m0 = blockIdx.x * 64;
    const int cy = blockIdx.y;

    const ushort_t* WT; int nloc;
    if (cy < 8)       { WT = WqT; nloc = cy * 128; }
    else if (cy < 10) { WT = WkT; nloc = (cy - 8) * 128; }
    else              { WT = WvT; nloc = (cy - 10) * 128; }

    f32x4 acc[2][4];
    #pragma unroll
    for (int i = 0; i < 2; ++i)
        #pragma unroll
        for (int j = 0; j < 4; ++j) acc[i][j] = (f32x4)0.f;

    auto stage = [&](int buf, int k0) {
        #pragma unroll
        for (int i = 0; i < 2; ++i) {
            const int r = wave * 16 + i * 8 + lq;
            cp16(&As[buf][(wave * 16 + i * 8) * 64],
                 xb + (size_t)(m0 + r) * 1024 + k0 + swz_st);
        }
        #pragma unroll
        for (int i = 0; i < 4; ++i) {
            const int r = wave * 32 + i * 8 + lq;
            cp16(&Bs[buf][(wave * 32 + i * 8) * 64],
                 WT + (size_t)(nloc + r) * 1024 + k0 + swz_st);
        }
    };

    stage(0, 0);
    __syncthreads();

    for (int kk = 0; kk < 16; ++kk) {
        const int cur = kk & 1;
        if (kk + 1 < 16) stage(cur ^ 1, (kk + 1) * 64);

        const ushort_t* Ac = &As[cur][0];
        const ushort_t* Bc = &Bs[cur][0];
        #pragma unroll
        for (int hh = 0; hh < 2; ++hh) {
            const int fsw = hh ? fsw1 : fsw0;
            short8 av[2], bv[4];
            #pragma unroll
            for (int i = 0; i < 2; ++i)
                av[i] = *(const short8*)&Ac[(wr * 32 + i * 16 + l15) * 64 + fsw];
            #pragma unroll
            for (int j = 0; j < 4; ++j)
                bv[j] = *(const short8*)&Bc[(wc * 64 + j * 16 + l15) * 64 + fsw];
            #pragma unroll
            for (int i = 0; i < 2; ++i)
                #pragma unroll
                for (int j = 0; j < 4; ++j)
                    acc[i][j] = __builtin_amdgcn_mfma_f32_16x16x32_bf16(
                        av[i], bv[j], acc[i][j], 0, 0, 0);
        }
        __syncthreads();
    }

    if (cy < 10) {
        ushort_t* dst = (cy < 8) ? Qb : Kb;
        const float qs = (cy < 8) ? 0.125f : 1.0f;
        const int h = ((cy < 8) ? cy : (cy - 8)) * 2 + wc;
        #pragma unroll
        for (int i = 0; i < 2; ++i) {
            #pragma unroll
            for (int j = 0; j < 2; ++j) {
                const int d = j * 16 + l15;
                #pragma unroll
                for (int reg = 0; reg < 4; ++reg) {
                    const int s = m0 + wr * 32 + i * 16 + quad * 4 + reg;
                    const float c  = rc[s * 32 + d];
                    const float sn = rs[s * 32 + d];
                    const float v1 = acc[i][j][reg];
                    const float v2 = acc[i][j + 2][reg];
                    dst[((size_t)h * S_LEN + s) * HD + d]      = f2bf((v1 * c - v2 * sn) * qs);
                    dst[((size_t)h * S_LEN + s) * HD + d + 32] = f2bf((v2 * c + v1 * sn) * qs);
                }
            }
        }
    } else {
        const int vh = (cy - 10) * 2 + wc;
        #pragma unroll
        for (int i = 0; i < 2; ++i) {
            const int s0 = m0 + wr * 32 + i * 16 + quad * 4;
            #pragma unroll
            for (int j = 0; j < 4; ++j) {
                const int d = j * 16 + l15;
                ushort4v o = { f2bf(acc[i][j][0]), f2bf(acc[i][j][1]),
                               f2bf(acc[i][j][2]), f2bf(acc[i][j][3]) };
                *(ushort4v*)&Vtb[((size_t)vh * HD + d) * S_LEN + s0] = o;
            }
        }
    }
}

// ---------------------------------------------------------------------------
// MFMA flash attention, split-KV with constant-work blocks.
// Max-free softmax makes partials linear: block (h, qt, k) accumulates
// unnormalized (sum e*V, sum e) over kv-subtiles [8k, min(8k+8, qt+1)) and
// writes fp32 partials to slot k. grid (80, NH), 128 threads (2 waves, M=32).
// LDS 40 KB -> 4 blocks/CU = 2 waves/SIMD (r10's 1 wave/SIMD was the wall).
// Heavy blocks dispatch first (index reversal); fine-grained queue balances.
// ---------------------------------------------------------------------------
__global__ __launch_bounds__(128, 2) void attn_mfma(
    const ushort_t* __restrict__ Qb, const ushort_t* __restrict__ Kb,
    const ushort_t* __restrict__ Vtb, float* __restrict__ Opart,
    float* __restrict__ lpart)
{
    __shared__ ushort_t Ks[2][64 * 64];   // 16 KB [buf][kv][d] swizzled
    __shared__ ushort_t Vs[2][64 * 64];   // 16 KB [buf][d][kv] swizzled
    __shared__ ushort_t Ps[2][32 * 64];   // 8 KB wave-private P, swizzled

    const int t = threadIdx.x;
    const int lane = t & 63, wave = t >> 6;          // wave 0..1
    const int quad = lane >> 4, l15 = lane & 15;
    const int lq = lane >> 3, lr = lane & 7;
    const int swz_st = (lr ^ lq) * 8;
    const int l7 = l15 & 7;
    const int fsw0 = (quad ^ l7) * 8;
    const int fsw1 = ((quad + 4) ^ l7) * 8;

    // work map: x -> (qt, split k). splits/head: qt 0-7:1, 8-15:2, 16-23:3,
    // 24-31:4 (80 blocks/head). Reverse so heavy blocks dispatch first.
    const int x = 79 - blockIdx.x;
    int qt, k;
    if (x < 8)       { qt = x;               k = 0; }
    else if (x < 24) { qt = 8 + (x - 8) / 2;  k = (x - 8) & 1; }
    else if (x < 48) { qt = 16 + (x - 24) / 3; k = (x - 24) % 3; }
    else             { qt = 24 + (x - 48) / 4; k = (x - 48) & 3; }
    const int start = k * 8;
    const int end   = min(start + 8, qt + 1);
    const int nsub  = end - start;

    const int h   = blockIdx.y;
    const int q0  = qt * 64;
    const int kvh = h >> 2;
    const int wrow0 = q0 + wave * 32;

    const ushort_t* Qg = Qb + ((size_t)h * S_LEN + wrow0) * HD;
    const ushort_t* Kg = Kb + (size_t)kvh * S_LEN * HD;
    const ushort_t* Vg = Vtb + (size_t)kvh * HD * S_LEN;

    // Q A-frags (pre-scaled by 0.125)
    short8 aq[2][2];
    #pragma unroll
    for (int i = 0; i < 2; ++i) {
        aq[i][0] = *(const short8*)(Qg + (size_t)(i * 16 + l15) * HD + quad * 8);
        aq[i][1] = *(const short8*)(Qg + (size_t)(i * 16 + l15) * HD + 32 + quad * 8);
    }

    float ps[2][4];
    f32x4 Oacc[2][4];
    #pragma unroll
    for (int i = 0; i < 2; ++i)
        #pragma unroll
        for (int jb = 0; jb < 4; ++jb) { Oacc[i][jb] = (f32x4)0.f; ps[i][jb] = 0.f; }

    auto stage = [&](int buf, int kvt) {
        const int kvbase = kvt * 64;
        #pragma unroll
        for (int i = 0; i < 4; ++i) {
            const int r = wave * 32 + i * 8 + lq;
            cp16(&Ks[buf][(wave * 32 + i * 8) * 64],
                 Kg + (size_t)(kvbase + r) * 64 + swz_st);
            cp16(&Vs[buf][(wave * 32 + i * 8) * 64],
                 Vg + (size_t)r * 2048 + kvbase + swz_st);
        }
    };

    stage(0, start);
    __syncthreads();

    ushort_t* Pw = &Ps[wave][0];

    for (int ssub = 0; ssub < nsub; ++ssub) {
        const int cur = ssub & 1;
        if (ssub + 1 < nsub) stage(cur ^ 1, start + ssub + 1);

        const int kvt = start + ssub;
        const int kv0 = kvt * 64;
        const ushort_t* Kc = &Ks[cur][0];
        const ushort_t* Vc = &Vs[cur][0];

        // S = Q K^T (K frags shared across both row tiles)
        f32x4 sv[2][4];
        #pragma unroll
        for (int jb = 0; jb < 4; ++jb) {
            short8 b0 = *(const short8*)&Kc[(jb * 16 + l15) * 64 + fsw0];
            short8 b1 = *(const short8*)&Kc[(jb * 16 + l15) * 64 + fsw1];
            #pragma unroll
            for (int i = 0; i < 2; ++i) {
                f32x4 z = (f32x4)0.f;
                z = __builtin_amdgcn_mfma_f32_16x16x32_bf16(aq[i][0], b0, z, 0, 0, 0);
                z = __builtin_amdgcn_mfma_f32_16x16x32_bf16(aq[i][1], b1, z, 0, 0, 0);
                sv[i][jb] = z;
            }
        }

        // max-free softmax: P = exp(s) (scale folded into Q); diag mask only
        const bool diag = (kvt == qt);
        #pragma unroll
        for (int i = 0; i < 2; ++i)
            #pragma unroll
            for (int jb = 0; jb < 4; ++jb) {
                const int col = kv0 + jb * 16 + l15;
                #pragma unroll
                for (int reg = 0; reg < 4; ++reg) {
                    float e = __expf(sv[i][jb][reg]);
                    if (diag && col > wrow0 + i * 16 + quad * 4 + reg) e = 0.f;
                    sv[i][jb][reg] = e;
                    ps[i][reg] += e;
                }
            }

        // P: C-layout -> swizzled wave-private LDS (truncation pack)
        #pragma unroll
        for (int i = 0; i < 2; ++i)
            #pragma unroll
            for (int jb = 0; jb < 4; ++jb)
                #pragma unroll
                for (int reg = 0; reg < 4; ++reg) {
                    const int row = i * 16 + quad * 4 + reg;
                    const int seg = (jb * 2 + (l15 >> 3)) ^ (row & 7);
                    Pw[row * 64 + seg * 8 + (l15 & 7)] =
                        (ushort_t)(__float_as_uint(sv[i][jb][reg]) >> 16);
                }

        short8 pf[2][2];
        #pragma unroll
        for (int i = 0; i < 2; ++i) {
            pf[i][0] = *(const short8*)&Pw[(i * 16 + l15) * 64 + fsw0];
            pf[i][1] = *(const short8*)&Pw[(i * 16 + l15) * 64 + fsw1];
        }

        // O += P V (V frags shared across both row tiles)
        #pragma unroll
        for (int jb = 0; jb < 4; ++jb) {
            short8 v0 = *(const short8*)&Vc[(jb * 16 + l15) * 64 + fsw0];
            short8 v1 = *(const short8*)&Vc[(jb * 16 + l15) * 64 + fsw1];
            #pragma unroll
            for (int i = 0; i < 2; ++i) {
                Oacc[i][jb] = __builtin_amdgcn_mfma_f32_16x16x32_bf16(
                    pf[i][0], v0, Oacc[i][jb], 0, 0, 0);
                Oacc[i][jb] = __builtin_amdgcn_mfma_f32_16x16x32_bf16(
                    pf[i][1], v1, Oacc[i][jb], 0, 0, 0);
            }
        }

        __syncthreads();
    }

    // write unnormalized partials to slot k (fp32); per-row l reduced once
    float* Op = Opart + (size_t)k * S_LEN * D_MODEL;
    float* lp = lpart + (size_t)k * S_LEN * NH;
    #pragma unroll
    for (int i = 0; i < 2; ++i)
        #pragma unroll
        for (int reg = 0; reg < 4; ++reg) {
            float l = ps[i][reg];
            l += __shfl_xor(l, 1);
            l += __shfl_xor(l, 2);
            l += __shfl_xor(l, 4);
            l += __shfl_xor(l, 8);
            const int s = wrow0 + i * 16 + quad * 4 + reg;
            if (l15 == 0) lp[s * NH + h] = l;
            #pragma unroll
            for (int jb = 0; jb < 4; ++jb)
                Op[(size_t)s * D_MODEL + h * HD + jb * 16 + l15] = Oacc[i][jb][reg];
        }
}

// ---------------------------------------------------------------------------
// Combine split-KV partials: attnb[s][c] = sum_k Opart[k][s][c] / sum_k l.
// grid 2048 (one block per row), 256 threads x 4 cols.
// ---------------------------------------------------------------------------
__global__ __launch_bounds__(256) void attn_combine(
    const float* __restrict__ Opart, const float* __restrict__ lpart,
    ushort_t* __restrict__ attnb)
{
    const int s  = blockIdx.x;
    const int qt = s >> 6;
    const int nk = (qt >> 3) + 1;
    const int c0 = threadIdx.x * 4;
    const int h  = c0 >> 6;

    float4 acc = *(const float4*)(Opart + (size_t)s * D_MODEL + c0);
    float  l   = lpart[s * NH + h];
    for (int k = 1; k < nk; ++k) {
        float4 a = *(const float4*)(Opart + (size_t)k * S_LEN * D_MODEL
                                    + (size_t)s * D_MODEL + c0);
        acc.x += a.x; acc.y += a.y; acc.z += a.z; acc.w += a.w;
        l += lpart[(size_t)k * S_LEN * NH + s * NH + h];
    }
    const float inv = 1.f / l;
    ushort4v o = { f2bf(acc.x * inv), f2bf(acc.y * inv),
                   f2bf(acc.z * inv), f2bf(acc.w * inv) };
    *(ushort4v*)(attnb + (size_t)s * D_MODEL + c0) = o;
}

// ---------------------------------------------------------------------------
// Output projection. 64x64 tile, BK=64, swizzled dbuf LDS. grid (32,16).
// ---------------------------------------------------------------------------
__global__ __launch_bounds__(256, 2) void gemm_out_mfma(
    const ushort_t* __restrict__ Ab, const ushort_t* __restrict__ WoT,
    float* __restrict__ out)
{
    __shared__ ushort_t As[2][64 * 64];
    __shared__ ushort_t Bs[2][64 * 64];

    const int t = threadIdx.x;
    const int lane = t & 63, wave = t >> 6;
    const int wr = wave >> 1, wc = wave & 1;
    const int quad = lane >> 4, l15 = lane & 15;
    const int lq = lane >> 3, lr = lane & 7;
    const int swz_st = (lr ^ lq) * 8;
    const int l7 = l15 & 7;
    const int fsw0 = (quad ^ l7) * 8;
    const int fsw1 = ((quad + 4) ^ l7) * 8;

    const int m0 = blockIdx.x * 64;
    const int n0 = blockIdx.y * 64;

    f32x4 acc[2][2];
    #pragma unroll
    for (int i = 0; i < 2; ++i)
        #pragma unroll
        for (int j = 0; j < 2; ++j) acc[i][j] = (f32x4)0.f;

    auto stage = [&](int buf, int k0) {
        #pragma unroll
        for (int i = 0; i < 2; ++i) {
            const int r = wave * 16 + i * 8 + lq;
            cp16(&As[buf][(wave * 16 + i * 8) * 64],
                 Ab + (size_t)(m0 + r) * 1024 + k0 + swz_st);
            cp16(&Bs[buf][(wave * 16 + i * 8) * 64],
                 WoT + (size_t)(n0 + r) * 1024 + k0 + swz_st);
        }
    };

    stage(0, 0);
    __syncthreads();

    for (int kk = 0; kk < 16; ++kk) {
        const int cur = kk & 1;
        if (kk + 1 < 16) stage(cur ^ 1, (kk + 1) * 64);

        const ushort_t* Ac = &As[cur][0];
        const ushort_t* Bc = &Bs[cur][0];
        #pragma unroll
        for (int hh = 0; hh < 2; ++hh) {
            const int fsw = hh ? fsw1 : fsw0;
            short8 av[2], bv[2];
            #pragma unroll
            for (int i = 0; i < 2; ++i)
                av[i] = *(const short8*)&Ac[(wr * 32 + i * 16 + l15) * 64 + fsw];
            #pragma unroll
            for (int j = 0; j < 2; ++j)
                bv[j] = *(const short8*)&Bc[(wc * 32 + j * 16 + l15) * 64 + fsw];
            #pragma unroll
            for (int i = 0; i < 2; ++i)
                #pragma unroll
                for (int j = 0; j < 2; ++j)
                    acc[i][j] = __builtin_amdgcn_mfma_f32_16x16x32_bf16(
                        av[i], bv[j], acc[i][j], 0, 0, 0);
        }
        __syncthreads();
    }

    #pragma unroll
    for (int i = 0; i < 2; ++i)
        #pragma unroll
        for (int reg = 0; reg < 4; ++reg) {
            const int s = m0 + wr * 32 + i * 16 + quad * 4 + reg;
            #pragma unroll
            for (int j = 0; j < 2; ++j)
                out[(size_t)s * D_MODEL + n0 + wc * 32 + j * 16 + l15] = acc[i][j][reg];
        }
}

// ---------------------------------------------------------------------------
extern "C" void kernel_launch(void* const* d_in, const int* in_sizes, int n_in,
                              void* d_out, int out_size, void* d_ws, size_t ws_size,
                              hipStream_t stream)
{
    const float* x  = (const float*)d_in[0];
    const float* rc = (const float*)d_in[1];
    const float* rs = (const float*)d_in[2];
    const float* Wq = (const float*)d_in[3];
    const float* Wk = (const float*)d_in[4];
    const float* Wv = (const float*)d_in[5];
    const float* Wo = (const float*)d_in[6];
    float* out = (float*)d_out;

    ushort_t* xb   = (ushort_t*)d_ws;                          // 2048*1024
    ushort_t* WqT  = xb   + (size_t)2048 * 1024;               // 1024*1024
    ushort_t* WkT  = WqT  + (size_t)1024 * 1024;               //  256*1024
    ushort_t* WvT  = WkT  + (size_t)256 * 1024;                //  256*1024
    ushort_t* WoT  = WvT  + (size_t)256 * 1024;                // 1024*1024
    ushort_t* Qb   = WoT  + (size_t)1024 * 1024;               // 16*2048*64
    ushort_t* Kb   = Qb   + (size_t)NH * S_LEN * HD;           //  4*2048*64
    ushort_t* Vtb  = Kb   + (size_t)NKV * S_LEN * HD;          //  4*64*2048
    ushort_t* attnb= Vtb  + (size_t)NKV * HD * S_LEN;          // 2048*1024
    // fp32 split-KV partials (aligned region after the ushort buffers)
    float* Opart = (float*)(attnb + (size_t)S_LEN * D_MODEL);  // 4*2048*1024 f32
    float* lpart = Opart + (size_t)4 * S_LEN * D_MODEL;        // 4*2048*16 f32
    // total ws use: ~19.5 MB + 32.5 MB = 52 MB

    prep_kernel<<<dim3(16, 16, 5), 256, 0, stream>>>(x, xb, Wq, Wk, Wv, Wo,
                                                     WqT, WkT, WvT, WoT);
    gemm_qkv_mfma<<<dim3(32, 12), 256, 0, stream>>>(xb, WqT, WkT, WvT,
                                                    rc, rs, Qb, Kb, Vtb);
    attn_mfma<<<dim3(80, NH), 128, 0, stream>>>(Qb, Kb, Vtb, Opart, lpart);
    attn_combine<<<2048, 256, 0, stream>>>(Opart, lpart, attnb);
    gemm_out_mfma<<<dim3(32, 16), 256, 0, stream>>>(attnb, WoT, out);
}